// Round 1
// baseline (2355.358 us; speedup 1.0000x reference)
//
#include <hip/hip_runtime.h>
#include <hip/hip_bf16.h>

// HierarchicalDecouplingModule: 7-branch single-query MHA.
// Key identity: q = tokens[i] broadcast over batch -> K-projection GEMMs collapse
// to g[i,h,:] = (Wq tok + bq)_h^T Wk_h ; score[b,h,l] = g[i,h]·src_l[b] * 0.125.
// V path: o = sum_l diag(attn_l) (src_l @ Wv^T) + bv  (bf16 GEMMs, epilogue-scaled,
// RMW-accumulated across sequential per-l kernels), then out = o @ Wout^T + b_out.

#define DD 1024
#define HH 16
#define BB 8192
#define NBR 7

using f32x4 = __attribute__((ext_vector_type(4))) float;
using s16x8 = __attribute__((ext_vector_type(8))) short;

// ---------------- prep: convert Wv, Wout slices to bf16 ----------------
__global__ __launch_bounds__(256) void conv_k(const float* __restrict__ w_in,
                                              const float* __restrict__ w_out,
                                              __hip_bfloat16* __restrict__ wv,
                                              __hip_bfloat16* __restrict__ wo) {
  size_t idx = (size_t)blockIdx.x * 256 + threadIdx.x;     // 2 * 1,835,008 threads
  size_t half = (size_t)NBR * DD * DD / 4;                 // 1,835,008
  bool second = idx >= half;
  size_t e = (second ? idx - half : idx) * 4;
  const float* src;
  __hip_bfloat16* dst;
  if (second) { src = w_out + e; dst = wo + e; }
  else {
    size_t i = e >> 20, rem = e & 1048575;
    size_t n = rem >> 10, k = rem & 1023;
    src = w_in + (i * 3072 + 2048 + n) * 1024 + k;         // Wv rows = w_in[i][2D + n]
    dst = wv + e;
  }
  float4 v = *(const float4*)src;
  union { __hip_bfloat16 h[4]; uint2 u; } t;
  t.h[0] = __float2bfloat16(v.x); t.h[1] = __float2bfloat16(v.y);
  t.h[2] = __float2bfloat16(v.z); t.h[3] = __float2bfloat16(v.w);
  *(uint2*)dst = t.u;
}

// ---------------- prep: qvec[i,d'] = Wq_i[d',:]·tok_i + bq ----------------
__global__ __launch_bounds__(256) void qvec_k(const float* __restrict__ w_in,
                                              const float* __restrict__ tokens,
                                              const float* __restrict__ b_in,
                                              float* __restrict__ qvec) {
  int out = blockIdx.x * 4 + (threadIdx.x >> 6);   // 7168 outputs, wave per output
  int lane = threadIdx.x & 63;
  int i = out >> 10, dp = out & 1023;
  const float4* row = (const float4*)(w_in + ((size_t)i * 3072 + dp) * 1024);
  const float4* tok = (const float4*)(tokens + (size_t)i * 1024);
  float p = 0.f;
#pragma unroll
  for (int c = 0; c < 4; c++) {
    float4 a = row[lane + 64 * c];
    float4 t = tok[lane + 64 * c];
    p += a.x * t.x + a.y * t.y + a.z * t.z + a.w * t.w;
  }
  p += __shfl_xor(p, 1);  p += __shfl_xor(p, 2);  p += __shfl_xor(p, 4);
  p += __shfl_xor(p, 8);  p += __shfl_xor(p, 16); p += __shfl_xor(p, 32);
  if (lane == 0) qvec[out] = p + b_in[(size_t)i * 3072 + dp];
}

// ---------------- prep: g[i,h,d] = 0.125 * sum_j qvec[i,h*64+j] * Wk_i[h*64+j, d] ----------------
__global__ __launch_bounds__(256) void g_k(const float* __restrict__ w_in,
                                           const float* __restrict__ qvec,
                                           float* __restrict__ g) {
  int i = blockIdx.x >> 4, h = blockIdx.x & 15;
  int t = threadIdx.x;
  float acc[4] = {0.f, 0.f, 0.f, 0.f};
  const float* wkbase = w_in + ((size_t)i * 3072 + 1024 + h * 64) * 1024;
  const float* qv = qvec + i * 1024 + h * 64;
  for (int j = 0; j < 64; j++) {
    float q = qv[j];
    const float* r = wkbase + (size_t)j * 1024;
#pragma unroll
    for (int c = 0; c < 4; c++) acc[c] += q * r[t + 256 * c];
  }
#pragma unroll
  for (int c = 0; c < 4; c++)
    g[((size_t)(i * 16 + h)) * 1024 + t + 256 * c] = acc[c] * 0.125f;
}

// ---------------- scores + softmax -> attn[i,b,h,l] (f32) ----------------
__global__ __launch_bounds__(256) void scores_k(const float* __restrict__ s0,
                                                const float* __restrict__ s1,
                                                const float* __restrict__ s2,
                                                const float* __restrict__ s3,
                                                const float* __restrict__ g,
                                                float* __restrict__ attn) {
  __shared__ float sc[16][7][16][4];   // 28KB
  const int tid = threadIdx.x;
  const int grp = tid >> 4, l16 = tid & 15;     // 16-lane group per batch element
  const int b = blockIdx.x * 16 + grp;
  // (i,l) pairs encoded i*4+l, per source {cls, face, boundary, bg}
  const int pairs0[7] = {0, 4, 8, 12, 16, 20, 24};
  const int pairs1[4] = {1, 13, 17, 25};
  const int pairs2[4] = {5, 14, 21, 26};
  const int pairs3[4] = {9, 18, 22, 27};
  const float* srcs[4] = {s0, s1, s2, s3};
#pragma unroll
  for (int s = 0; s < 4; s++) {
    const float4* sp = (const float4*)(srcs[s] + (size_t)b * DD);
    float4 sv[16];
#pragma unroll
    for (int t = 0; t < 16; t++) sv[t] = sp[l16 + 16 * t];   // lane-interleaved, coalesced
    const int np = (s == 0) ? 7 : 4;
    const int* pr = (s == 0) ? pairs0 : (s == 1) ? pairs1 : (s == 2) ? pairs2 : pairs3;
    for (int pi = 0; pi < np; pi++) {
      int v = pr[pi];
      int i = v >> 2, l = v & 3;
      for (int h = 0; h < 16; h++) {
        const float4* gp = (const float4*)(g + (size_t)(i * 16 + h) * DD);
        float p = 0.f;
#pragma unroll
        for (int t = 0; t < 16; t++) {
          float4 a = sv[t]; float4 q = gp[l16 + 16 * t];
          p += a.x * q.x + a.y * q.y + a.z * q.z + a.w * q.w;
        }
        p += __shfl_xor(p, 1); p += __shfl_xor(p, 2);
        p += __shfl_xor(p, 4); p += __shfl_xor(p, 8);
        if (l16 == 0) sc[grp][i][h][l] = p;
      }
    }
  }
  __syncthreads();
  const int Ls[7] = {2, 2, 2, 3, 3, 3, 4};
  for (int it = tid; it < 16 * 112; it += 256) {
    int bl = it / 112, r = it % 112;
    int i = r >> 4, h = r & 15;
    int L = Ls[i];
    float v0 = sc[bl][i][h][0], v1 = sc[bl][i][h][1];
    float v2 = (L > 2) ? sc[bl][i][h][2] : -1e30f;
    float v3 = (L > 3) ? sc[bl][i][h][3] : -1e30f;
    float m = fmaxf(fmaxf(v0, v1), fmaxf(v2, v3));
    float e0 = __expf(v0 - m), e1 = __expf(v1 - m);
    float e2 = (L > 2) ? __expf(v2 - m) : 0.f;
    float e3 = (L > 3) ? __expf(v3 - m) : 0.f;
    float inv = 1.f / (e0 + e1 + e2 + e3);
    int bb2 = blockIdx.x * 16 + bl;
    float* ap = attn + (((size_t)i * BB + bb2) * HH + h) * 4;
    ap[0] = e0 * inv; ap[1] = e1 * inv; ap[2] = e2 * inv; ap[3] = e3 * inv;
  }
}

// ---------------- bf16 B^T GEMM, 128x128x32 tile, 4 waves ----------------
// C[m,n] = sum_k A[m,k] * B[n,k].  AMODE: 0 = A f32 (convert on stage), 1 = A bf16.
// EPI: 0 = o := attn*acc + bv ; 1 = o += attn*acc (bf16 RMW) ; 2 = fout := acc + bias.
template <int AMODE, int EPI>
__global__ __launch_bounds__(256) void gemm_bt(const void* __restrict__ Aptr,
                                               const __hip_bfloat16* __restrict__ Bp,
                                               const float* __restrict__ attn,
                                               int branch, int lidx,
                                               __hip_bfloat16* __restrict__ o,
                                               const float* __restrict__ bias,
                                               float* __restrict__ fout) {
  constexpr int K = 1024;
  __shared__ __align__(16) __hip_bfloat16 As[128 * 32];
  __shared__ __align__(16) __hip_bfloat16 Bs[128 * 32];
  const int tid = threadIdx.x;
  const int lane = tid & 63;
  const int wid = tid >> 6;
  const int wm = wid >> 1, wn = wid & 1;          // 2x2 waves, 64x64 each
  const int row0 = blockIdx.x * 128;
  const int col0 = blockIdx.y * 128;
  const int frow = lane & 15;
  const int fk = (lane >> 4) * 8;
  f32x4 acc[4][4];
#pragma unroll
  for (int m = 0; m < 4; m++)
#pragma unroll
    for (int n = 0; n < 4; n++) acc[m][n] = (f32x4){0.f, 0.f, 0.f, 0.f};

  for (int k0 = 0; k0 < K; k0 += 32) {
#pragma unroll
    for (int c = 0; c < 2; c++) {
      int idx = tid + c * 256;                    // 512 chunks of 8 bf16
      int r = idx >> 2, kb = (idx & 3) * 8;
      if (AMODE == 0) {
        const float* a = (const float*)Aptr + (size_t)(row0 + r) * K + k0 + kb;
        float4 v0 = *(const float4*)a;
        float4 v1 = *(const float4*)(a + 4);
        union { __hip_bfloat16 h[8]; uint4 u; } t;
        t.h[0] = __float2bfloat16(v0.x); t.h[1] = __float2bfloat16(v0.y);
        t.h[2] = __float2bfloat16(v0.z); t.h[3] = __float2bfloat16(v0.w);
        t.h[4] = __float2bfloat16(v1.x); t.h[5] = __float2bfloat16(v1.y);
        t.h[6] = __float2bfloat16(v1.z); t.h[7] = __float2bfloat16(v1.w);
        *(uint4*)&As[r * 32 + kb] = t.u;
      } else {
        const __hip_bfloat16* a = (const __hip_bfloat16*)Aptr + (size_t)(row0 + r) * K + k0 + kb;
        *(uint4*)&As[r * 32 + kb] = *(const uint4*)a;
      }
      const __hip_bfloat16* bsrc = Bp + (size_t)(col0 + r) * K + k0 + kb;
      *(uint4*)&Bs[r * 32 + kb] = *(const uint4*)bsrc;
    }
    __syncthreads();
    s16x8 af[4], bfr[4];
#pragma unroll
    for (int m = 0; m < 4; m++)
      af[m] = *(const s16x8*)&As[(wm * 64 + m * 16 + frow) * 32 + fk];
#pragma unroll
    for (int n = 0; n < 4; n++)
      bfr[n] = *(const s16x8*)&Bs[(wn * 64 + n * 16 + frow) * 32 + fk];
#pragma unroll
    for (int m = 0; m < 4; m++)
#pragma unroll
      for (int n = 0; n < 4; n++)
        acc[m][n] = __builtin_amdgcn_mfma_f32_16x16x32_bf16(af[m], bfr[n], acc[m][n], 0, 0, 0);
    __syncthreads();
  }

#pragma unroll
  for (int n = 0; n < 4; n++) {
    int col = col0 + wn * 64 + n * 16 + frow;
    int h = col >> 6;
#pragma unroll
    for (int m = 0; m < 4; m++) {
      int rb = row0 + wm * 64 + m * 16 + ((lane >> 4) << 2);
#pragma unroll
      for (int j = 0; j < 4; j++) {
        int b = rb + j;
        float v = acc[m][n][j];
        if (EPI == 0) {
          float aw = attn[(((size_t)branch * BB + b) * HH + h) * 4 + lidx];
          o[(size_t)b * DD + col] = __float2bfloat16(v * aw + bias[col]);
        } else if (EPI == 1) {
          float aw = attn[(((size_t)branch * BB + b) * HH + h) * 4 + lidx];
          __hip_bfloat16* p = o + (size_t)b * DD + col;
          *p = __float2bfloat16(__bfloat162float(*p) + v * aw);
        } else {
          fout[(size_t)b * DD + col] = v + bias[col];
        }
      }
    }
  }
}

extern "C" void kernel_launch(void* const* d_in, const int* in_sizes, int n_in,
                              void* d_out, int out_size, void* d_ws, size_t ws_size,
                              hipStream_t stream) {
  const float* cls   = (const float*)d_in[0];
  const float* face  = (const float*)d_in[1];
  const float* bdry  = (const float*)d_in[2];
  const float* bgv   = (const float*)d_in[3];
  const float* tok   = (const float*)d_in[4];
  const float* w_in  = (const float*)d_in[5];
  const float* b_in  = (const float*)d_in[6];
  const float* w_out = (const float*)d_in[7];
  const float* b_out = (const float*)d_in[8];
  float* out = (float*)d_out;
  char* ws = (char*)d_ws;

  // ws layout (~63 MB total)
  float* g    = (float*)ws;                                   // 448 KB
  float* qvec = (float*)(ws + (512ull << 10));                // 28 KB
  float* attn = (float*)(ws + (1ull << 20));                  // 14.7 MB
  __hip_bfloat16* wv   = (__hip_bfloat16*)(ws + (16ull << 20)); // 14.7 MB
  __hip_bfloat16* wo   = (__hip_bfloat16*)(ws + (31ull << 20)); // 14.7 MB
  __hip_bfloat16* obuf = (__hip_bfloat16*)(ws + (46ull << 20)); // 16.8 MB

  conv_k<<<dim3(14336), dim3(256), 0, stream>>>(w_in, w_out, wv, wo);
  qvec_k<<<dim3(1792), dim3(256), 0, stream>>>(w_in, tok, b_in, qvec);
  g_k<<<dim3(112), dim3(256), 0, stream>>>(w_in, qvec, g);
  scores_k<<<dim3(512), dim3(256), 0, stream>>>(cls, face, bdry, bgv, g, attn);

  const float* srcs[4] = {cls, face, bdry, bgv};
  const int bl[7][4] = {{0,1,-1,-1},{0,2,-1,-1},{0,3,-1,-1},
                        {0,1,2,-1},{0,1,3,-1},{0,2,3,-1},{0,1,2,3}};
  const int Ls[7] = {2, 2, 2, 3, 3, 3, 4};
  dim3 gg(64, 8);
  for (int i = 0; i < NBR; i++) {
    const __hip_bfloat16* Bv = wv + (size_t)i * 1024 * 1024;
    const float* bv = b_in + (size_t)i * 3072 + 2048;
    for (int l = 0; l < Ls[i]; l++) {
      const float* A = srcs[bl[i][l]];
      if (l == 0)
        gemm_bt<0, 0><<<gg, 256, 0, stream>>>(A, Bv, attn, i, l, obuf, bv, nullptr);
      else
        gemm_bt<0, 1><<<gg, 256, 0, stream>>>(A, Bv, attn, i, l, obuf, bv, nullptr);
    }
    gemm_bt<1, 2><<<gg, 256, 0, stream>>>(obuf, wo + (size_t)i * 1024 * 1024, attn, i, 0,
                                          obuf, b_out + (size_t)i * 1024,
                                          out + (size_t)i * BB * DD);
  }
}